// Round 5
// baseline (73.834 us; speedup 1.0000x reference)
//
#include <hip/hip_runtime.h>
#include <stdint.h>

#define HH 2048
#define WW 2048
#define NPIX (HH * WW)
#define WPR (WW / 32)   // 64 words per row
#define NBLK 512        // fused-kernel grid: 2 blocks/CU on 256 CUs -> all co-resident

// distinct squared distances in the 9x9 window (sorted ascending)
__device__ __constant__ int c_d2s[14] = {1, 2, 4, 5, 8, 9, 10, 13, 16, 17, 18, 20, 25, 32};

__host__ __device__ constexpr int g_of(int d2) {
  switch (d2) {
    case 1:  return 0;  case 2:  return 1;  case 4:  return 2;  case 5:  return 3;
    case 8:  return 4;  case 9:  return 5;  case 10: return 6;  case 13: return 7;
    case 16: return 8;  case 17: return 9;  case 18: return 10; case 20: return 11;
    case 25: return 12; case 32: return 13;
  }
  return 15;
}

// ---------------- K1: channel sum + bit-pack mask (8 px/thread) + barrier reset ----------------
__global__ __launch_bounds__(256) void k_prep(const float* __restrict__ t,
                                              uint8_t* __restrict__ chsum,
                                              uint8_t* __restrict__ bits8,
                                              uint32_t* __restrict__ done) {
  if (blockIdx.x == 0 && threadIdx.x == 0) *done = 0;  // visible to k_fused (kernel order)
  int p = blockIdx.x * 256 + threadIdx.x;  // handles pixels 8p..8p+7
  const float4* t4 = (const float4*)t;
  float s[8] = {0, 0, 0, 0, 0, 0, 0, 0};
#pragma unroll
  for (int ch = 0; ch < 5; ++ch) {
    const float4* base = t4 + (size_t)ch * (NPIX / 4) + 2 * (size_t)p;
    float4 a = base[0], b = base[1];
    s[0] += a.x; s[1] += a.y; s[2] += a.z; s[3] += a.w;
    s[4] += b.x; s[5] += b.y; s[6] += b.z; s[7] += b.w;
  }
  uint32_t lo = 0, hi = 0, mb = 0;
#pragma unroll
  for (int i = 0; i < 8; ++i) {
    uint32_t c = (uint32_t)s[i];  // 0..5 exactly
    if (i < 4) lo |= c << (8 * i);
    else       hi |= c << (8 * (i - 4));
    mb |= (c > 0 ? 1u : 0u) << i;
  }
  ((uint2*)chsum)[p] = make_uint2(lo, hi);
  bits8[p] = (uint8_t)mb;
}

// ---------------- K2: fused contour + grid-barrier min/max + LUT normalize ----------------
// Each block owns 4 rows; per-pixel codes (c | g<<3) stay in registers.
// Grid barrier: packed per-block min/max via agent-scope atomic store + arrival counter.
__global__ __launch_bounds__(256, 2) void k_fused(const uint32_t* __restrict__ bits,
                                                  const uint8_t* __restrict__ chsum,
                                                  unsigned long long* __restrict__ blockred,
                                                  uint32_t* __restrict__ done,
                                                  float* __restrict__ out) {
  __shared__ float tab[16];
  __shared__ float red[8];
  __shared__ float lut[128];

  if (threadIdx.x < 16) {
    float v = 0.0f;
    if (threadIdx.x < 14) {
      float d = sqrtf((float)c_d2s[threadIdx.x]);
      v = 1.0f / (d + 1e-10f);  // contour value: 1/min_d
    }
    tab[threadIdx.x] = v;  // tab[14]=tab[15]=0 (no differing neighbor)
  }
  __syncthreads();

  int tid = blockIdx.x * 256 + threadIdx.x;
  int y  = tid >> 6;   // row
  int wx = tid & 63;   // word within row

  uint32_t rowP[9], rowC[9], rowN[9];
#pragma unroll
  for (int dy = 0; dy < 9; ++dy) {
    int yy = y + dy - 4;
    yy = yy < 0 ? 0 : (yy > HH - 1 ? HH - 1 : yy);
    const uint32_t* r = bits + yy * WPR;
    uint32_t cur = r[wx];
    uint32_t prev = (wx > 0)       ? r[wx - 1] : ((cur & 1u) ? 0xFFFFFFFFu : 0u);
    uint32_t next = (wx < WPR - 1) ? r[wx + 1] : ((cur >> 31) ? 0xFFFFFFFFu : 0u);
    rowP[dy] = prev; rowC[dy] = cur; rowN[dy] = next;
  }
  uint32_t W0 = rowC[4];  // center row word (each pixel's own mask bit)

  uint32_t B[14];
#pragma unroll
  for (int g = 0; g < 14; ++g) B[g] = 0u;

#pragma unroll
  for (int dy = 0; dy < 9; ++dy) {
#pragma unroll
    for (int dx = -4; dx <= 4; ++dx) {
      if (dy == 4 && dx == 0) continue;
      const int ddy = dy - 4;
      const int d2 = ddy * ddy + dx * dx;
      const int g = g_of(d2);
      uint32_t s;
      if (dx > 0)      s = (rowC[dy] >> dx) | (rowN[dy] << (32 - dx));
      else if (dx < 0) s = (rowC[dy] << (-dx)) | (rowP[dy] >> (32 + dx));
      else             s = rowC[dy];
      B[g] |= s ^ W0;  // bit set where neighbor differs from center
    }
  }

  // resolve min-distance group per pixel via bit-planes (ascending d2)
  uint32_t R = 0u, p0 = 0u, p1 = 0u, p2 = 0u, p3 = 0u;
#pragma unroll
  for (int g = 0; g < 14; ++g) {
    uint32_t nw = B[g] & ~R;
    R |= nw;
    if (g & 1) p0 |= nw;
    if (g & 2) p1 |= nw;
    if (g & 4) p2 |= nw;
    if (g & 8) p3 |= nw;
  }
  uint32_t un = ~R;  // unresolved -> g = 14 (0b1110) -> contour 0
  p1 |= un; p2 |= un; p3 |= un;

  // chsum bytes for this word's 32 pixels
  const uint4* cs4 = (const uint4*)(chsum + y * WW + wx * 32);
  uint4 ca = cs4[0], cb = cs4[1];
  uint32_t comp[8] = {ca.x, ca.y, ca.z, ca.w, cb.x, cb.y, cb.z, cb.w};

  uint32_t cw[8];
  float lmin = 3.4e38f, lmax = 0.0f;
#pragma unroll
  for (int i = 0; i < 32; ++i) {
    uint32_t g = ((p0 >> i) & 1) | (((p1 >> i) & 1) << 1) | (((p2 >> i) & 1) << 2) |
                 (((p3 >> i) & 1) << 3);
    uint32_t c = (comp[i >> 2] >> ((i & 3) * 8)) & 0xFFu;
    float wv = (float)c + tab[g];
    wv = wv * wv;
    lmin = fminf(lmin, wv);
    lmax = fmaxf(lmax, wv);
    uint32_t code = c | (g << 3);
    if ((i & 3) == 0) cw[i >> 2] = code;
    else              cw[i >> 2] |= code << ((i & 3) * 8);
  }

  // block reduce min/max -> one packed agent-scope store + arrival
#pragma unroll
  for (int off = 1; off < 64; off <<= 1) {
    lmin = fminf(lmin, __shfl_xor(lmin, off));
    lmax = fmaxf(lmax, __shfl_xor(lmax, off));
  }
  int wv = threadIdx.x >> 6;
  if ((threadIdx.x & 63) == 0) { red[wv] = lmin; red[wv + 4] = lmax; }
  __syncthreads();
  if (threadIdx.x == 0) {
    float mn = fminf(fminf(red[0], red[1]), fminf(red[2], red[3]));
    float mx = fmaxf(fmaxf(red[4], red[5]), fmaxf(red[6], red[7]));
    unsigned long long pk = (unsigned long long)__float_as_uint(mn) |
                            ((unsigned long long)__float_as_uint(mx) << 32);
    __hip_atomic_store(&blockred[blockIdx.x], pk, __ATOMIC_RELEASE, __HIP_MEMORY_SCOPE_AGENT);
    __hip_atomic_fetch_add(done, 1u, __ATOMIC_RELEASE, __HIP_MEMORY_SCOPE_AGENT);
    // grid barrier: all 512 blocks co-resident (launch_bounds(256,2) -> 2 blocks/CU)
    while (__hip_atomic_load(done, __ATOMIC_ACQUIRE, __HIP_MEMORY_SCOPE_AGENT) < NBLK) {
      __builtin_amdgcn_s_sleep(2);
    }
  }
  __syncthreads();

  // every block redundantly folds the 512 pairs (atomic loads bypass stale caches)
  {
    int t = threadIdx.x;
    unsigned long long a = __hip_atomic_load(&blockred[t], __ATOMIC_RELAXED, __HIP_MEMORY_SCOPE_AGENT);
    unsigned long long b = __hip_atomic_load(&blockred[t + 256], __ATOMIC_RELAXED, __HIP_MEMORY_SCOPE_AGENT);
    float mn = fminf(__uint_as_float((uint32_t)a), __uint_as_float((uint32_t)b));
    float mx = fmaxf(__uint_as_float((uint32_t)(a >> 32)), __uint_as_float((uint32_t)(b >> 32)));
#pragma unroll
    for (int off = 1; off < 64; off <<= 1) {
      mn = fminf(mn, __shfl_xor(mn, off));
      mx = fmaxf(mx, __shfl_xor(mx, off));
    }
    if ((t & 63) == 0) { red[t >> 6] = mn; red[(t >> 6) + 4] = mx; }
  }
  __syncthreads();

  if (threadIdx.x < 128) {
    float mn = fminf(fminf(red[0], red[1]), fminf(red[2], red[3]));
    float mx = fmaxf(fmaxf(red[4], red[5]), fmaxf(red[6], red[7]));
    float inv = 1.0f / (mx - mn + 1e-10f);
    int c = threadIdx.x & 7;   // 0..5 used
    int g = threadIdx.x >> 3;  // 0..15
    float contour = 0.0f;
    if (g < 14) contour = 1.0f / (sqrtf((float)c_d2s[g]) + 1e-10f);
    float wvv = (float)c + contour;
    wvv = wvv * wvv;
    lut[threadIdx.x] = (c > 0) ? (wvv - mn) * inv : 0.0f;
  }
  __syncthreads();

  // decode register codes -> output (thread owns 32 consecutive px = 128B region)
  float4* ob = (float4*)(out + y * WW + wx * 32);
#pragma unroll
  for (int w = 0; w < 8; ++w) {
    uint32_t cwv = cw[w];
    ob[w] = make_float4(lut[cwv & 127], lut[(cwv >> 8) & 127],
                        lut[(cwv >> 16) & 127], lut[(cwv >> 24) & 127]);
  }
}

extern "C" void kernel_launch(void* const* d_in, const int* in_sizes, int n_in,
                              void* d_out, int out_size, void* d_ws, size_t ws_size,
                              hipStream_t stream) {
  const float* target = (const float*)d_in[0];
  uint8_t* chsum = (uint8_t*)d_ws;                                     // 4 MB
  uint8_t* bits8 = (uint8_t*)d_ws + (4u << 20);                        // 512 KB
  unsigned long long* blockred =
      (unsigned long long*)((char*)d_ws + (4u << 20) + (512u << 10));  // 4 KB
  uint32_t* done = (uint32_t*)((char*)blockred + NBLK * 8);

  float* out = (float*)d_out;

  k_prep<<<NPIX / 8 / 256, 256, 0, stream>>>(target, chsum, bits8, done);
  k_fused<<<NBLK, 256, 0, stream>>>((const uint32_t*)bits8, chsum, blockred, done, out);
}

// Round 6
// 37.411 us; speedup vs baseline: 1.9736x; 1.9736x over previous
//
#include <hip/hip_runtime.h>
#include <stdint.h>

#define HH 2048
#define WW 2048
#define NPIX (HH * WW)
#define WPR (WW / 32)   // 64 words per row
#define NBLKC 1024      // k_contour grid: 2 threads per 32-px word

typedef float f32x4 __attribute__((ext_vector_type(4)));
typedef uint32_t u32x4 __attribute__((ext_vector_type(4)));

// distinct squared distances in the 9x9 window (sorted ascending)
__device__ __constant__ int c_d2s[14] = {1, 2, 4, 5, 8, 9, 10, 13, 16, 17, 18, 20, 25, 32};

__host__ __device__ constexpr int g_of(int d2) {
  switch (d2) {
    case 1:  return 0;  case 2:  return 1;  case 4:  return 2;  case 5:  return 3;
    case 8:  return 4;  case 9:  return 5;  case 10: return 6;  case 13: return 7;
    case 16: return 8;  case 17: return 9;  case 18: return 10; case 20: return 11;
    case 25: return 12; case 32: return 13;
  }
  return 15;
}

// ---------------- K1: channel sum + bit-pack mask (8 px/thread) ----------------
__global__ __launch_bounds__(256) void k_prep(const float* __restrict__ t,
                                              uint8_t* __restrict__ chsum,
                                              uint8_t* __restrict__ bits8) {
  int p = blockIdx.x * 256 + threadIdx.x;  // handles pixels 8p..8p+7
  const f32x4* t4 = (const f32x4*)t;
  float s[8] = {0, 0, 0, 0, 0, 0, 0, 0};
#pragma unroll
  for (int ch = 0; ch < 5; ++ch) {
    const f32x4* base = t4 + (size_t)ch * (NPIX / 4) + 2 * (size_t)p;
    f32x4 a = __builtin_nontemporal_load(base);      // streaming: don't thrash L2
    f32x4 b = __builtin_nontemporal_load(base + 1);
    s[0] += a[0]; s[1] += a[1]; s[2] += a[2]; s[3] += a[3];
    s[4] += b[0]; s[5] += b[1]; s[6] += b[2]; s[7] += b[3];
  }
  uint32_t lo = 0, hi = 0, mb = 0;
#pragma unroll
  for (int i = 0; i < 8; ++i) {
    uint32_t c = (uint32_t)s[i];  // 0..5 exactly
    if (i < 4) lo |= c << (8 * i);
    else       hi |= c << (8 * (i - 4));
    mb |= (c > 0 ? 1u : 0u) << i;
  }
  ((uint2*)chsum)[p] = make_uint2(lo, hi);
  bits8[p] = (uint8_t)mb;
}

// ---------------- K2: bit-parallel contour -> code bytes + per-block min/max ----------------
// 2 threads per 32-px word (h = half). codes buffer doubles as chsum input: each
// thread reads its own 16 chsum bytes, then overwrites them with code bytes
// (c | g<<3). No cross-thread overlap.
__global__ __launch_bounds__(256) void k_contour(const uint32_t* __restrict__ bits,
                                                 uint8_t* codes,
                                                 float2* __restrict__ blockred) {
  __shared__ float tab2[128];  // (c + contour(g))^2 for code = c | g<<3
  __shared__ float red[8];
  int t = threadIdx.x;
  if (t < 128) {
    int c = t & 7, g = t >> 3;
    float contour = (g < 14) ? 1.0f / (sqrtf((float)c_d2s[g]) + 1e-10f) : 0.0f;
    float wv = (float)c + contour;
    tab2[t] = wv * wv;
  }
  __syncthreads();

  int tid = blockIdx.x * 256 + t;
  int w = tid >> 1;      // word index
  int h = tid & 1;       // half: px 16h..16h+15
  int y  = w >> 6;       // row
  int wx = w & 63;       // word within row

  uint32_t rowP[9], rowC[9], rowN[9];
#pragma unroll
  for (int dy = 0; dy < 9; ++dy) {
    int yy = y + dy - 4;
    yy = yy < 0 ? 0 : (yy > HH - 1 ? HH - 1 : yy);
    const uint32_t* r = bits + yy * WPR;
    uint32_t cur = r[wx];
    uint32_t prev = (wx > 0)       ? r[wx - 1] : ((cur & 1u) ? 0xFFFFFFFFu : 0u);
    uint32_t next = (wx < WPR - 1) ? r[wx + 1] : ((cur >> 31) ? 0xFFFFFFFFu : 0u);
    rowP[dy] = prev; rowC[dy] = cur; rowN[dy] = next;
  }
  uint32_t W0 = rowC[4];  // center row word (each pixel's own mask bit)

  uint32_t B[14];
#pragma unroll
  for (int g = 0; g < 14; ++g) B[g] = 0u;

#pragma unroll
  for (int dy = 0; dy < 9; ++dy) {
#pragma unroll
    for (int dx = -4; dx <= 4; ++dx) {
      if (dy == 4 && dx == 0) continue;
      const int ddy = dy - 4;
      const int d2 = ddy * ddy + dx * dx;
      const int g = g_of(d2);
      uint32_t s;
      if (dx > 0)      s = (rowC[dy] >> dx) | (rowN[dy] << (32 - dx));
      else if (dx < 0) s = (rowC[dy] << (-dx)) | (rowP[dy] >> (32 + dx));
      else             s = rowC[dy];
      B[g] |= s ^ W0;  // bit set where neighbor differs from center
    }
  }

  // resolve min-distance group per pixel via bit-planes (ascending d2)
  uint32_t R = 0u, p0 = 0u, p1 = 0u, p2 = 0u, p3 = 0u;
#pragma unroll
  for (int g = 0; g < 14; ++g) {
    uint32_t nw = B[g] & ~R;
    R |= nw;
    if (g & 1) p0 |= nw;
    if (g & 2) p1 |= nw;
    if (g & 4) p2 |= nw;
    if (g & 8) p3 |= nw;
  }
  uint32_t un = ~R;  // unresolved -> g = 14 (0b1110) -> contour 0
  p1 |= un; p2 |= un; p3 |= un;

  // this thread's 16 chsum bytes
  u32x4 comp = *(const u32x4*)(codes + y * WW + wx * 32 + h * 16);

  // word-parallel code packing: spread nibble bits to byte lanes
  const uint32_t M = 0x00204081u, SEL = 0x01010101u;
  uint32_t cw[4];
  float lmin = 3.4e38f, lmax = 0.0f;
#pragma unroll
  for (int j = 0; j < 4; ++j) {
    int J = 4 * (h * 4 + j);  // bit offset of this 4-px group
    uint32_t n0 = (p0 >> J) & 0xF, n1 = (p1 >> J) & 0xF;
    uint32_t n2 = (p2 >> J) & 0xF, n3 = (p3 >> J) & 0xF;
    uint32_t gb = (((n0 * M) & SEL) << 3) | (((n1 * M) & SEL) << 4) |
                  (((n2 * M) & SEL) << 5) | (((n3 * M) & SEL) << 6);
    uint32_t cwj = comp[j] | gb;  // byte = c | g<<3
    cw[j] = cwj;
    float a = tab2[cwj & 127],        b = tab2[(cwj >> 8) & 127];
    float c = tab2[(cwj >> 16) & 127], d = tab2[(cwj >> 24) & 127];
    lmin = fminf(lmin, fminf(fminf(a, b), fminf(c, d)));
    lmax = fmaxf(lmax, fmaxf(fmaxf(a, b), fmaxf(c, d)));
  }

  // write code bytes over the chsum region (same 16 bytes this thread read)
  u32x4 cws = {cw[0], cw[1], cw[2], cw[3]};
  *(u32x4*)(codes + y * WW + wx * 32 + h * 16) = cws;

  // wave reduce min/max, then block reduce, ONE store per block (no atomics)
#pragma unroll
  for (int off = 1; off < 64; off <<= 1) {
    lmin = fminf(lmin, __shfl_xor(lmin, off));
    lmax = fmaxf(lmax, __shfl_xor(lmax, off));
  }
  int wv = t >> 6;
  if ((t & 63) == 0) { red[wv] = lmin; red[wv + 4] = lmax; }
  __syncthreads();
  if (t == 0) {
    float mn = fminf(fminf(red[0], red[1]), fminf(red[2], red[3]));
    float mx = fmaxf(fmaxf(red[4], red[5]), fmaxf(red[6], red[7]));
    blockred[blockIdx.x] = make_float2(mn, mx);
  }
}

// ---------------- K3: inline 1024-pair min/max fold + LUT normalize (8 px/thread) ----------------
__global__ __launch_bounds__(256) void k_norm(const uint8_t* __restrict__ codes,
                                              const float2* __restrict__ blockred,
                                              float* __restrict__ out) {
  __shared__ float lut[128];
  __shared__ float red[8];
  __shared__ float smm[2];
  int t = threadIdx.x;

  // every block redundantly folds the 1024 per-block pairs (8 KB, L2-hot)
  {
    float mn = 3.4e38f, mx = 0.0f;
#pragma unroll
    for (int k = 0; k < 4; ++k) {
      float2 a = blockred[t + 256 * k];
      mn = fminf(mn, a.x);
      mx = fmaxf(mx, a.y);
    }
#pragma unroll
    for (int off = 1; off < 64; off <<= 1) {
      mn = fminf(mn, __shfl_xor(mn, off));
      mx = fmaxf(mx, __shfl_xor(mx, off));
    }
    int wv = t >> 6;
    if ((t & 63) == 0) { red[wv] = mn; red[wv + 4] = mx; }
  }
  __syncthreads();
  if (t == 0) {
    smm[0] = fminf(fminf(red[0], red[1]), fminf(red[2], red[3]));
    smm[1] = fmaxf(fmaxf(red[4], red[5]), fmaxf(red[6], red[7]));
  }
  __syncthreads();

  if (t < 128) {
    float mn = smm[0];
    float inv = 1.0f / (smm[1] - mn + 1e-10f);
    int c = t & 7;   // 0..5 used
    int g = t >> 3;  // 0..15
    float contour = 0.0f;
    if (g < 14) contour = 1.0f / (sqrtf((float)c_d2s[g]) + 1e-10f);
    float wv = (float)c + contour;
    wv = wv * wv;
    lut[t] = (c > 0) ? (wv - mn) * inv : 0.0f;
  }
  __syncthreads();

  int p = blockIdx.x * 256 + t;  // handles 8 pixels
  uint2 cwv = ((const uint2*)codes)[p];
  f32x4 v0 = {lut[cwv.x & 127], lut[(cwv.x >> 8) & 127],
              lut[(cwv.x >> 16) & 127], lut[(cwv.x >> 24) & 127]};
  f32x4 v1 = {lut[cwv.y & 127], lut[(cwv.y >> 8) & 127],
              lut[(cwv.y >> 16) & 127], lut[(cwv.y >> 24) & 127]};
  f32x4* o4 = (f32x4*)out + 2 * (size_t)p;
  __builtin_nontemporal_store(v0, o4);      // out is never re-read
  __builtin_nontemporal_store(v1, o4 + 1);
}

extern "C" void kernel_launch(void* const* d_in, const int* in_sizes, int n_in,
                              void* d_out, int out_size, void* d_ws, size_t ws_size,
                              hipStream_t stream) {
  const float* target = (const float*)d_in[0];
  uint8_t* codes = (uint8_t*)d_ws;                               // chsum -> codes, 4 MB
  uint8_t* bits8 = (uint8_t*)d_ws + (4u << 20);                  // 512 KB packed mask
  float2* blockred = (float2*)((char*)d_ws + (4u << 20) + (512u << 10));  // 8 KB

  float* out = (float*)d_out;

  k_prep<<<NPIX / 8 / 256, 256, 0, stream>>>(target, codes, bits8);
  k_contour<<<NBLKC, 256, 0, stream>>>((const uint32_t*)bits8, codes, blockred);
  k_norm<<<NPIX / 8 / 256, 256, 0, stream>>>(codes, blockred, out);
}

// Round 7
// 35.948 us; speedup vs baseline: 2.0539x; 1.0407x over previous
//
#include <hip/hip_runtime.h>
#include <stdint.h>

#define HH 2048
#define WW 2048
#define NPIX (HH * WW)
#define WPR (WW / 32)   // 64 words per row
#define NBLKC 1024      // k_contour grid: 2 threads per 32-px word -> 16 waves/CU

typedef float f32x4 __attribute__((ext_vector_type(4)));
typedef uint32_t u32x4 __attribute__((ext_vector_type(4)));

// distinct squared distances in the 9x9 window (sorted ascending)
__device__ __constant__ int c_d2s[14] = {1, 2, 4, 5, 8, 9, 10, 13, 16, 17, 18, 20, 25, 32};

__host__ __device__ constexpr int g_of(int d2) {
  switch (d2) {
    case 1:  return 0;  case 2:  return 1;  case 4:  return 2;  case 5:  return 3;
    case 8:  return 4;  case 9:  return 5;  case 10: return 6;  case 13: return 7;
    case 16: return 8;  case 17: return 9;  case 18: return 10; case 20: return 11;
    case 25: return 12; case 32: return 13;
  }
  return 15;
}

// ---------------- K1: channel sum + bit-pack mask (8 px/thread) ----------------
__global__ __launch_bounds__(256) void k_prep(const float* __restrict__ t,
                                              uint8_t* __restrict__ chsum,
                                              uint8_t* __restrict__ bits8) {
  int p = blockIdx.x * 256 + threadIdx.x;  // handles pixels 8p..8p+7
  const float4* t4 = (const float4*)t;
  float s[8] = {0, 0, 0, 0, 0, 0, 0, 0};
#pragma unroll
  for (int ch = 0; ch < 5; ++ch) {
    const float4* base = t4 + (size_t)ch * (NPIX / 4) + 2 * (size_t)p;
    float4 a = base[0], b = base[1];
    s[0] += a.x; s[1] += a.y; s[2] += a.z; s[3] += a.w;
    s[4] += b.x; s[5] += b.y; s[6] += b.z; s[7] += b.w;
  }
  uint32_t lo = 0, hi = 0, mb = 0;
#pragma unroll
  for (int i = 0; i < 8; ++i) {
    uint32_t c = (uint32_t)s[i];  // 0..5 exactly
    if (i < 4) lo |= c << (8 * i);
    else       hi |= c << (8 * (i - 4));
    mb |= (c > 0 ? 1u : 0u) << i;
  }
  ((uint2*)chsum)[p] = make_uint2(lo, hi);
  bits8[p] = (uint8_t)mb;
}

// ---------------- K2: bit-parallel contour -> code bytes + per-block min/max ----------------
// 2 threads per 32-px word (h = half). codes buffer doubles as chsum input: each
// thread reads its own 16 chsum bytes, then overwrites them with code bytes
// (c | g<<3). No cross-thread overlap.
__global__ __launch_bounds__(256) void k_contour(const uint32_t* __restrict__ bits,
                                                 uint8_t* codes,
                                                 float2* __restrict__ blockred) {
  __shared__ float tab2[128];  // (c + contour(g))^2 for code = c | g<<3
  __shared__ float red[8];
  int t = threadIdx.x;
  if (t < 128) {
    int c = t & 7, g = t >> 3;
    float contour = (g < 14) ? 1.0f / (sqrtf((float)c_d2s[g]) + 1e-10f) : 0.0f;
    float wv = (float)c + contour;
    tab2[t] = wv * wv;
  }
  __syncthreads();

  int tid = blockIdx.x * 256 + t;
  int w = tid >> 1;      // word index
  int h = tid & 1;       // half: px 16h..16h+15
  int y  = w >> 6;       // row
  int wx = w & 63;       // word within row

  uint32_t rowP[9], rowC[9], rowN[9];
#pragma unroll
  for (int dy = 0; dy < 9; ++dy) {
    int yy = y + dy - 4;
    yy = yy < 0 ? 0 : (yy > HH - 1 ? HH - 1 : yy);
    const uint32_t* r = bits + yy * WPR;
    uint32_t cur = r[wx];
    uint32_t prev = (wx > 0)       ? r[wx - 1] : ((cur & 1u) ? 0xFFFFFFFFu : 0u);
    uint32_t next = (wx < WPR - 1) ? r[wx + 1] : ((cur >> 31) ? 0xFFFFFFFFu : 0u);
    rowP[dy] = prev; rowC[dy] = cur; rowN[dy] = next;
  }
  uint32_t W0 = rowC[4];  // center row word (each pixel's own mask bit)

  uint32_t B[14];
#pragma unroll
  for (int g = 0; g < 14; ++g) B[g] = 0u;

#pragma unroll
  for (int dy = 0; dy < 9; ++dy) {
#pragma unroll
    for (int dx = -4; dx <= 4; ++dx) {
      if (dy == 4 && dx == 0) continue;
      const int ddy = dy - 4;
      const int d2 = ddy * ddy + dx * dx;
      const int g = g_of(d2);
      uint32_t s;
      if (dx > 0)      s = (rowC[dy] >> dx) | (rowN[dy] << (32 - dx));
      else if (dx < 0) s = (rowC[dy] << (-dx)) | (rowP[dy] >> (32 + dx));
      else             s = rowC[dy];
      B[g] |= s ^ W0;  // bit set where neighbor differs from center
    }
  }

  // resolve min-distance group per pixel via bit-planes (ascending d2)
  uint32_t R = 0u, p0 = 0u, p1 = 0u, p2 = 0u, p3 = 0u;
#pragma unroll
  for (int g = 0; g < 14; ++g) {
    uint32_t nw = B[g] & ~R;
    R |= nw;
    if (g & 1) p0 |= nw;
    if (g & 2) p1 |= nw;
    if (g & 4) p2 |= nw;
    if (g & 8) p3 |= nw;
  }
  uint32_t un = ~R;  // unresolved -> g = 14 (0b1110) -> contour 0
  p1 |= un; p2 |= un; p3 |= un;

  // this thread's 16 chsum bytes
  u32x4 comp = *(const u32x4*)(codes + y * WW + wx * 32 + h * 16);

  // word-parallel code packing: spread nibble bits to byte lanes
  const uint32_t M = 0x00204081u, SEL = 0x01010101u;
  uint32_t cw[4];
  float lmin = 3.4e38f, lmax = 0.0f;
#pragma unroll
  for (int j = 0; j < 4; ++j) {
    int J = 4 * (h * 4 + j);  // bit offset of this 4-px group
    uint32_t n0 = (p0 >> J) & 0xF, n1 = (p1 >> J) & 0xF;
    uint32_t n2 = (p2 >> J) & 0xF, n3 = (p3 >> J) & 0xF;
    uint32_t gb = (((n0 * M) & SEL) << 3) | (((n1 * M) & SEL) << 4) |
                  (((n2 * M) & SEL) << 5) | (((n3 * M) & SEL) << 6);
    uint32_t cwj = comp[j] | gb;  // byte = c | g<<3
    cw[j] = cwj;
    float a = tab2[cwj & 127],        b = tab2[(cwj >> 8) & 127];
    float c = tab2[(cwj >> 16) & 127], d = tab2[(cwj >> 24) & 127];
    lmin = fminf(lmin, fminf(fminf(a, b), fminf(c, d)));
    lmax = fmaxf(lmax, fmaxf(fmaxf(a, b), fmaxf(c, d)));
  }

  // write code bytes over the chsum region (same 16 bytes this thread read)
  u32x4 cws = {cw[0], cw[1], cw[2], cw[3]};
  *(u32x4*)(codes + y * WW + wx * 32 + h * 16) = cws;

  // wave reduce min/max, then block reduce, ONE store per block (no atomics)
#pragma unroll
  for (int off = 1; off < 64; off <<= 1) {
    lmin = fminf(lmin, __shfl_xor(lmin, off));
    lmax = fmaxf(lmax, __shfl_xor(lmax, off));
  }
  int wv = t >> 6;
  if ((t & 63) == 0) { red[wv] = lmin; red[wv + 4] = lmax; }
  __syncthreads();
  if (t == 0) {
    float mn = fminf(fminf(red[0], red[1]), fminf(red[2], red[3]));
    float mx = fmaxf(fmaxf(red[4], red[5]), fmaxf(red[6], red[7]));
    blockred[blockIdx.x] = make_float2(mn, mx);
  }
}

// ---------------- K2b: fold 1024 per-block pairs into minmax ----------------
__global__ __launch_bounds__(256) void k_reduce(const float2* __restrict__ br,
                                                unsigned* __restrict__ minmax) {
  __shared__ float s[8];
  int t = threadIdx.x;
  float mn = 3.4e38f, mx = 0.0f;
#pragma unroll
  for (int k = 0; k < 4; ++k) {
    float2 a = br[t + 256 * k];
    mn = fminf(mn, a.x);
    mx = fmaxf(mx, a.y);
  }
#pragma unroll
  for (int off = 1; off < 64; off <<= 1) {
    mn = fminf(mn, __shfl_xor(mn, off));
    mx = fmaxf(mx, __shfl_xor(mx, off));
  }
  int wv = t >> 6;
  if ((t & 63) == 0) { s[wv] = mn; s[wv + 4] = mx; }
  __syncthreads();
  if (t == 0) {
    mn = fminf(fminf(s[0], s[1]), fminf(s[2], s[3]));
    mx = fmaxf(fmaxf(s[4], s[5]), fmaxf(s[6], s[7]));
    minmax[0] = __float_as_uint(mn);
    minmax[1] = __float_as_uint(mx);
  }
}

// ---------------- K3: LUT normalize + mask (8 px/thread) ----------------
__global__ __launch_bounds__(256) void k_norm(const uint8_t* __restrict__ codes,
                                              const unsigned* __restrict__ minmax,
                                              float* __restrict__ out) {
  __shared__ float lut[128];
  int t = threadIdx.x;
  if (t < 128) {
    float mn = __uint_as_float(minmax[0]);
    float mx = __uint_as_float(minmax[1]);
    float inv = 1.0f / (mx - mn + 1e-10f);
    int c = t & 7;   // 0..5 used
    int g = t >> 3;  // 0..15
    float contour = 0.0f;
    if (g < 14) contour = 1.0f / (sqrtf((float)c_d2s[g]) + 1e-10f);
    float wv = (float)c + contour;
    wv = wv * wv;
    lut[t] = (c > 0) ? (wv - mn) * inv : 0.0f;
  }
  __syncthreads();

  int p = blockIdx.x * 256 + t;  // handles 8 pixels
  uint2 cwv = ((const uint2*)codes)[p];
  float4 v0 = make_float4(lut[cwv.x & 127], lut[(cwv.x >> 8) & 127],
                          lut[(cwv.x >> 16) & 127], lut[(cwv.x >> 24) & 127]);
  float4 v1 = make_float4(lut[cwv.y & 127], lut[(cwv.y >> 8) & 127],
                          lut[(cwv.y >> 16) & 127], lut[(cwv.y >> 24) & 127]);
  float4* o4 = (float4*)out + 2 * (size_t)p;
  o4[0] = v0;
  o4[1] = v1;
}

extern "C" void kernel_launch(void* const* d_in, const int* in_sizes, int n_in,
                              void* d_out, int out_size, void* d_ws, size_t ws_size,
                              hipStream_t stream) {
  const float* target = (const float*)d_in[0];
  uint8_t* codes = (uint8_t*)d_ws;                               // chsum -> codes, 4 MB
  uint8_t* bits8 = (uint8_t*)d_ws + (4u << 20);                  // 512 KB packed mask
  float2* blockred = (float2*)((char*)d_ws + (4u << 20) + (512u << 10));  // 8 KB
  unsigned* minmax = (unsigned*)((char*)blockred + NBLKC * sizeof(float2));

  float* out = (float*)d_out;

  k_prep<<<NPIX / 8 / 256, 256, 0, stream>>>(target, codes, bits8);
  k_contour<<<NBLKC, 256, 0, stream>>>((const uint32_t*)bits8, codes, blockred);
  k_reduce<<<1, 256, 0, stream>>>(blockred, minmax);
  k_norm<<<NPIX / 8 / 256, 256, 0, stream>>>(codes, minmax, out);
}